// Round 1
// 447.649 us; speedup vs baseline: 1.0481x; 1.0481x over previous
//
#include <hip/hip_runtime.h>
#include <hip/hip_bf16.h>

// Problem constants (linear_nce): N=8192, H=1024, V=50257, K=4096
#define NROWS 8192
#define HDIM  1024
#define VDIM  50257
#define KNOISE 4096

typedef short  bf16x8 __attribute__((ext_vector_type(8)));
typedef float  f32x4  __attribute__((ext_vector_type(4)));

__device__ __forceinline__ unsigned short f2bf(float x) {
    union { float f; unsigned int u; } v; v.f = x;
    unsigned int r = (v.u + 0x7fffu + ((v.u >> 16) & 1u)) >> 16;
    return (unsigned short)r;
}

// async global->LDS 16B copy: LDS dest is wave-uniform base + lane*16
__device__ __forceinline__ void gload16(const void* g, void* l) {
    __builtin_amdgcn_global_load_lds(
        (const __attribute__((address_space(1))) void*)g,
        (__attribute__((address_space(3))) void*)l, 16, 0, 0);
}

// ---------------------------------------------------------------------------
// Fused prep kernel (UNCHANGED from previous round):
//  blocks [0, NROWS):       pmt/pnt fp32 dot for row b; also convert input row
//                           -> bf16 into in_bf.
//  blocks [NROWS, NROWS+K): gather weight[noise] -> bf16 wn_bf, bn, un.
__global__ __launch_bounds__(256) void prep_kernel(
        const float* __restrict__ input,
        const float* __restrict__ weight,
        const float* __restrict__ bias,
        const float* __restrict__ unigram,
        const int* __restrict__ target,
        const int* __restrict__ noise,
        unsigned short* __restrict__ in_bf,
        unsigned short* __restrict__ wn_bf,
        float* __restrict__ bn,
        float* __restrict__ un,
        float* __restrict__ out_pmt,
        float* __restrict__ out_pnt) {
    const int tid = threadIdx.x;
    if (blockIdx.x < NROWS) {
        const int row = blockIdx.x;
        const int t = target[row];
        float4 a = ((const float4*)(input + (size_t)row * HDIM))[tid];
        ushort4 o;
        o.x = f2bf(a.x); o.y = f2bf(a.y); o.z = f2bf(a.z); o.w = f2bf(a.w);
        ((ushort4*)(in_bf + (size_t)row * HDIM))[tid] = o;
        float4 w = ((const float4*)(weight + (size_t)t * HDIM))[tid];
        float s = a.x * w.x + a.y * w.y + a.z * w.z + a.w * w.w;
        #pragma unroll
        for (int off = 32; off > 0; off >>= 1) s += __shfl_down(s, off);
        __shared__ float red[4];
        if ((tid & 63) == 0) red[tid >> 6] = s;
        __syncthreads();
        if (tid == 0) {
            float tot = red[0] + red[1] + red[2] + red[3];
            out_pmt[row] = expf(tot + bias[t]);
            out_pnt[row] = unigram[t];
        }
    } else {
        const int r = blockIdx.x - NROWS;       // 0..K-1
        const int idx = noise[r];
        float4 v = ((const float4*)(weight + (size_t)idx * HDIM))[tid];
        ushort4 o;
        o.x = f2bf(v.x); o.y = f2bf(v.y); o.z = f2bf(v.z); o.w = f2bf(v.w);
        ((ushort4*)(wn_bf + (size_t)r * HDIM))[tid] = o;
        if (tid == 0) { bn[r] = bias[idx]; un[r] = unigram[idx]; }
    }
}

// ---------------------------------------------------------------------------
// GEMM v2: 256x256 tile, BK=64, 512 threads (8 waves, 2Mx4N), 8-phase-class
// schedule with counted vmcnt (T3+T4), LDS XOR swizzle (T2), setprio (T5).
//
// LDS: full 160 KB = A-ring 5 x 16 KB half-tiles (+0) | B-ring 5 x 16 KB
// (+81920). A half-tile = 128 rows x 64 cols bf16, row-major (128 B rows),
// byte swizzle: byte ^= (row&7)<<4 (involution; applied on ds_read AND on the
// pre-swizzled global_load_lds source chunk).
//
// Schedule (half h = tile t halves {2t, 2t+1}; slot = h % 5):
//   prologue: stage A0 B0 A1 B1 A2 B2 (12 gloads); vmcnt(4); barrier
//   tile t, phase p in 0..3 (quadrant mih=p>>1, nih=p&1):
//     ds_read 8x A-frag + 4x B-frag b128 (tile t slots)
//     p0: stage A(2t+3)   p1: stage B(2t+3)
//     p2: 2x pnn float4 store, stage A(2t+4)   p3: stage B(2t+4)
//     barrier; lgkmcnt(0); setprio(1); 16 MFMA; setprio(0)
//     p3 only: vmcnt(6)  [t==14: vmcnt(2); t==15: none]
//     barrier
//   Slot-reuse safety: stage of half h (slot h%5) overwrites half h-5
//   (tile floor((h-5)/2) <= t-1), whose readers all passed tile t-1's final
//   barrier before any tile-t stage issues. Readiness: boundary vmcnt(6)
//   leaves exactly {2 stores + stage(2t+4)=4 gloads} in flight, forcing
//   halves 2t+3 and older complete before tile t+1's first ds_read.
#define BM 256
#define BN 256
#define ASLOT 16384
#define BRING_OFF 81920        // 5 * 16384
#define EPS_LD 68
#define SMEM_DYN 163840        // 160 KiB

__global__ __launch_bounds__(512, 2) void gemm_nce_kernel(
        const unsigned short* __restrict__ A,
        const unsigned short* __restrict__ Bt,
        const float* __restrict__ bn,
        const float* __restrict__ un,
        float* __restrict__ pmn,
        float* __restrict__ pnn) {
    extern __shared__ char smem[];

    const int tid  = threadIdx.x;          // 0..511
    const int wave = tid >> 6;             // 0..7
    const int lane = tid & 63;
    const int wm   = wave >> 2;            // 0..1  (M half)
    const int wn2  = wave & 3;             // 0..3  (N quarter)
    const int r    = lane & 15;
    const int q    = lane >> 4;
    const int swz  = (r & 7) << 4;

    // XCD-aware block swizzle: 512 blocks, 8 XCDs, share B-panel within XCD
    const int bid  = blockIdx.x;
    const int swzb = (bid & 7) * 64 + (bid >> 3);
    const int row0 = (swzb & 31) * BM;     // 32 row-blocks
    const int col0 = (swzb >> 5) * BN;     // 16 col-blocks

    // staging per-thread constants (pre-swizzled global source)
    const int lrow   = tid >> 3;                     // 0..63 (row for issue j0)
    const int lchunk = tid & 7;                      // 16B chunk within 128B row
    const int lsc    = lchunk ^ (lrow & 7);          // inverse-swizzled src chunk
    const unsigned short* gA = A  + (size_t)(row0 + lrow) * HDIM + lsc * 8;
    const unsigned short* gB = Bt + (size_t)(col0 + lrow) * HDIM + lsc * 8;
    char* ldsAw = smem + wave * 1024;                // + slot*16384 (+8192 for j1)
    char* ldsBw = smem + BRING_OFF + wave * 1024;

    auto stageA = [&](int h) {
        const unsigned short* g = gA + (size_t)((h & 1) * 128) * HDIM + (h >> 1) * 64;
        char* l = ldsAw + (h % 5) * ASLOT;
        gload16(g, l);
        gload16(g + 64 * HDIM, l + 8192);
    };
    auto stageB = [&](int h) {
        const unsigned short* g = gB + (size_t)((h & 1) * 128) * HDIM + (h >> 1) * 64;
        char* l = ldsBw + (h % 5) * ASLOT;
        gload16(g, l);
        gload16(g + 64 * HDIM, l + 8192);
    };

    // epilogue / pnn constants
    const int rrd = q;                    // 0..3
    const int crd = r * 4;                // 0..60
    const float4 unv4 = *(const float4*)&un[col0 + wn2 * 64 + crd];
    float bnv[4];
    #pragma unroll
    for (int ni = 0; ni < 4; ni++)
        bnv[ni] = bn[col0 + wn2 * 64 + ni * 16 + r];
    float* pnn_base = pnn + (size_t)(row0 + wm * 128 + rrd) * KNOISE
                          + col0 + wn2 * 64 + crd;

    f32x4 acc[8][4];
    #pragma unroll
    for (int mi = 0; mi < 8; mi++)
        #pragma unroll
        for (int ni = 0; ni < 4; ni++)
            acc[mi][ni] = (f32x4){0.f, 0.f, 0.f, 0.f};

    // prologue: halves 0,1,2 of both matrices
    stageA(0); stageB(0); stageA(1); stageB(1); stageA(2); stageB(2);
    asm volatile("s_waitcnt vmcnt(4)" ::: "memory");
    __builtin_amdgcn_s_barrier();

    int slotA = wm;              // (2t + wm) % 5
    int slotB = wn2 >> 1;        // (2t + (wn2>>1)) % 5
    const int koff0 = (q * 16) ^ swz;
    const int koff1 = (64 + q * 16) ^ swz;

    for (int t = 0; t < 16; ++t) {
        const char* As = smem + slotA * ASLOT;
        const char* Bs = smem + BRING_OFF + slotB * ASLOT;
        #pragma unroll
        for (int p = 0; p < 4; ++p) {
            const int mih = p >> 1, nih = p & 1;
            bf16x8 af[4][2], bv[2][2];
            #pragma unroll
            for (int m4 = 0; m4 < 4; ++m4) {
                const int rb = (mih * 64 + m4 * 16 + r) << 7;
                af[m4][0] = *(const bf16x8*)(As + rb + koff0);
                af[m4][1] = *(const bf16x8*)(As + rb + koff1);
            }
            #pragma unroll
            for (int n2 = 0; n2 < 2; ++n2) {
                const int cb = ((wn2 & 1) * 64 + nih * 32 + n2 * 16 + r) << 7;
                bv[n2][0] = *(const bf16x8*)(Bs + cb + koff0);
                bv[n2][1] = *(const bf16x8*)(Bs + cb + koff1);
            }
            if (p == 0)      { if (t <= 14) stageA(2 * t + 3); }
            else if (p == 1) { if (t <= 14) stageB(2 * t + 3); }
            else if (p == 2) {
                float* pb = pnn_base + (size_t)(8 * t) * KNOISE;
                *(float4*)pb = unv4;
                *(float4*)(pb + 4 * KNOISE) = unv4;
                if (t <= 13) stageA(2 * t + 4);
            } else           { if (t <= 13) stageB(2 * t + 4); }

            __builtin_amdgcn_s_barrier();
            asm volatile("s_waitcnt lgkmcnt(0)" ::: "memory");
            __builtin_amdgcn_sched_barrier(0);
            __builtin_amdgcn_s_setprio(1);
            #pragma unroll
            for (int m4 = 0; m4 < 4; ++m4)
                #pragma unroll
                for (int n2 = 0; n2 < 2; ++n2) {
                    f32x4 c = acc[mih * 4 + m4][nih * 2 + n2];
                    c = __builtin_amdgcn_mfma_f32_16x16x32_bf16(af[m4][0], bv[n2][0], c, 0, 0, 0);
                    c = __builtin_amdgcn_mfma_f32_16x16x32_bf16(af[m4][1], bv[n2][1], c, 0, 0, 0);
                    acc[mih * 4 + m4][nih * 2 + n2] = c;
                }
            __builtin_amdgcn_s_setprio(0);
            __builtin_amdgcn_sched_barrier(0);
            if (p == 3) {
                if (t < 14)       { asm volatile("s_waitcnt vmcnt(6)" ::: "memory"); }
                else if (t == 14) { asm volatile("s_waitcnt vmcnt(2)" ::: "memory"); }
            }
            __builtin_amdgcn_s_barrier();
        }
        slotA += 2; if (slotA >= 5) slotA -= 5;
        slotB += 2; if (slotB >= 5) slotB -= 5;
    }

    // ---- epilogue: exp(acc+bias) -> per-wave LDS transpose -> float4 stores
    // (after final barrier all ring reads are done; waves use disjoint regions)
    float* eps = (float*)smem + wave * (16 * EPS_LD);
    #pragma unroll
    for (int mi = 0; mi < 8; ++mi) {
        #pragma unroll
        for (int ni = 0; ni < 4; ++ni)
            #pragma unroll
            for (int j = 0; j < 4; ++j)
                eps[(q * 4 + j) * EPS_LD + ni * 16 + r] = __expf(acc[mi][ni][j] + bnv[ni]);
        __builtin_amdgcn_s_waitcnt(0xc07f);   // lgkmcnt(0) only
        #pragma unroll
        for (int j = 0; j < 4; ++j) {
            float4 v = *(float4*)&eps[(rrd * 4 + j) * EPS_LD + crd];
            size_t off = (size_t)(row0 + wm * 128 + mi * 16 + rrd * 4 + j) * KNOISE
                       + col0 + wn2 * 64 + crd;
            *(float4*)&pmn[off] = v;
        }
        __builtin_amdgcn_s_waitcnt(0xc07f);   // reads done before next mi overwrites
    }
}

// ---------------------------------------------------------------------------
extern "C" void kernel_launch(void* const* d_in, const int* in_sizes, int n_in,
                              void* d_out, int out_size, void* d_ws, size_t ws_size,
                              hipStream_t stream) {
    const float* input   = (const float*)d_in[0];
    const float* weight  = (const float*)d_in[1];
    const float* bias    = (const float*)d_in[2];
    const float* unigram = (const float*)d_in[3];
    const int*   target  = (const int*)d_in[4];
    const int*   noise   = (const int*)d_in[5];

    unsigned short* in_bf = (unsigned short*)d_ws;                    // 16 MB
    unsigned short* wn_bf = in_bf + (size_t)NROWS * HDIM;             // 8 MB
    float* bn = (float*)(wn_bf + (size_t)KNOISE * HDIM);
    float* un = bn + KNOISE;

    float* out = (float*)d_out;
    float* o_pmt = out;
    float* o_pnt = out + NROWS;
    float* o_pmn = out + 2 * NROWS;
    float* o_pnn = o_pmn + (size_t)NROWS * KNOISE;

    static bool attr_done = false;
    if (!attr_done) {
        (void)hipFuncSetAttribute(reinterpret_cast<const void*>(gemm_nce_kernel),
                                  hipFuncAttributeMaxDynamicSharedMemorySize,
                                  SMEM_DYN);
        attr_done = true;
    }

    prep_kernel<<<NROWS + KNOISE, 256, 0, stream>>>(
        input, weight, bias, unigram, target, noise,
        in_bf, wn_bf, bn, un, o_pmt, o_pnt);

    gemm_nce_kernel<<<512, 512, SMEM_DYN, stream>>>(
        in_bf, wn_bf, bn, un, o_pmn, o_pnn);
}

// Round 4
// 439.154 us; speedup vs baseline: 1.0683x; 1.0193x over previous
//
#include <hip/hip_runtime.h>
#include <hip/hip_bf16.h>

// Problem constants (linear_nce): N=8192, H=1024, V=50257, K=4096
#define NROWS 8192
#define HDIM  1024
#define VDIM  50257
#define KNOISE 4096

typedef short  bf16x8 __attribute__((ext_vector_type(8)));
typedef float  f32x4  __attribute__((ext_vector_type(4)));

__device__ __forceinline__ unsigned short f2bf(float x) {
    union { float f; unsigned int u; } v; v.f = x;
    unsigned int r = (v.u + 0x7fffu + ((v.u >> 16) & 1u)) >> 16;
    return (unsigned short)r;
}

// async global->LDS 16B copy: LDS dest is wave-uniform base + lane*16
__device__ __forceinline__ void gload16(const void* g, void* l) {
    __builtin_amdgcn_global_load_lds(
        (const __attribute__((address_space(1))) void*)g,
        (__attribute__((address_space(3))) void*)l, 16, 0, 0);
}

// ---------------------------------------------------------------------------
// Fused prep kernel (UNCHANGED):
//  blocks [0, NROWS):       pmt/pnt fp32 dot for row b; also convert input row
//                           -> bf16 into in_bf.
//  blocks [NROWS, NROWS+K): gather weight[noise] -> bf16 wn_bf, bn, un.
__global__ __launch_bounds__(256) void prep_kernel(
        const float* __restrict__ input,
        const float* __restrict__ weight,
        const float* __restrict__ bias,
        const float* __restrict__ unigram,
        const int* __restrict__ target,
        const int* __restrict__ noise,
        unsigned short* __restrict__ in_bf,
        unsigned short* __restrict__ wn_bf,
        float* __restrict__ bn,
        float* __restrict__ un,
        float* __restrict__ out_pmt,
        float* __restrict__ out_pnt) {
    const int tid = threadIdx.x;
    if (blockIdx.x < NROWS) {
        const int row = blockIdx.x;
        const int t = target[row];
        float4 a = ((const float4*)(input + (size_t)row * HDIM))[tid];
        ushort4 o;
        o.x = f2bf(a.x); o.y = f2bf(a.y); o.z = f2bf(a.z); o.w = f2bf(a.w);
        ((ushort4*)(in_bf + (size_t)row * HDIM))[tid] = o;
        float4 w = ((const float4*)(weight + (size_t)t * HDIM))[tid];
        float s = a.x * w.x + a.y * w.y + a.z * w.z + a.w * w.w;
        #pragma unroll
        for (int off = 32; off > 0; off >>= 1) s += __shfl_down(s, off);
        __shared__ float red[4];
        if ((tid & 63) == 0) red[tid >> 6] = s;
        __syncthreads();
        if (tid == 0) {
            float tot = red[0] + red[1] + red[2] + red[3];
            out_pmt[row] = expf(tot + bias[t]);
            out_pnt[row] = unigram[t];
        }
    } else {
        const int r = blockIdx.x - NROWS;       // 0..K-1
        const int idx = noise[r];
        float4 v = ((const float4*)(weight + (size_t)idx * HDIM))[tid];
        ushort4 o;
        o.x = f2bf(v.x); o.y = f2bf(v.y); o.z = f2bf(v.z); o.w = f2bf(v.w);
        ((ushort4*)(wn_bf + (size_t)r * HDIM))[tid] = o;
        if (tid == 0) { bn[r] = bias[idx]; un[r] = unigram[idx]; }
    }
}

// ---------------------------------------------------------------------------
// GEMM v3c: 256x256 tile, BK=64, 512 threads (8 waves, 2Mx4N).
//  - Gray-code phase order (mih,nih) = (0,0),(0,1),(1,1),(1,0):
//    af read once per mih-half (p0, p2), bv[2][2][2] held whole tile.
//    24 ds_read_b128/wave/tile (was 48 in v2).
//  - pnn store at p2 (v2's PROVEN queue position). vmcnt drains are
//    positional: issue order per tile must be A(2t+3), B(2t+3), st,
//    A(2t+4), B(2t+4) so boundary vmcnt(6) leaves {st, A(2t+4), B(2t+4)}
//    and everything tile t+1 reads is drained. (v3b's store-at-tile-start
//    left B(2t+3) undrained -> race -> absmax 5.9e-5 fail.)
//  - Non-temporal pnn/pmn stores via ext-vector f32x4.
// LDS: A-ring 5 x 16 KB half-tiles | B-ring 5 x 16 KB (+81920); half-tile =
// 128 rows x 64 cols bf16, 128 B rows, byte ^= (row&7)<<4 swizzle applied on
// read AND on the pre-swizzled global_load_lds source chunk.
#define BM 256
#define BN 256
#define ASLOT 16384
#define BRING_OFF 81920        // 5 * 16384
#define EPS_LD 68
#define SMEM_DYN 163840        // 160 KiB

__global__ __launch_bounds__(512, 2) void gemm_nce_kernel(
        const unsigned short* __restrict__ A,
        const unsigned short* __restrict__ Bt,
        const float* __restrict__ bn,
        const float* __restrict__ un,
        float* __restrict__ pmn,
        float* __restrict__ pnn) {
    extern __shared__ char smem[];

    const int tid  = threadIdx.x;          // 0..511
    const int wave = tid >> 6;             // 0..7
    const int lane = tid & 63;
    const int wm   = wave >> 2;            // 0..1  (M half)
    const int wn2  = wave & 3;             // 0..3  (N quarter)
    const int r    = lane & 15;
    const int q    = lane >> 4;
    const int swz  = (r & 7) << 4;

    // XCD-aware block swizzle: 512 blocks, 8 XCDs, share B-panel within XCD
    const int bid  = blockIdx.x;
    const int swzb = (bid & 7) * 64 + (bid >> 3);
    const int row0 = (swzb & 31) * BM;     // 32 row-blocks
    const int col0 = (swzb >> 5) * BN;     // 16 col-blocks

    // staging per-thread constants (pre-swizzled global source)
    const int lrow   = tid >> 3;                     // 0..63 (row for issue j0)
    const int lchunk = tid & 7;                      // 16B chunk within 128B row
    const int lsc    = lchunk ^ (lrow & 7);          // inverse-swizzled src chunk
    const unsigned short* gA = A  + (size_t)(row0 + lrow) * HDIM + lsc * 8;
    const unsigned short* gB = Bt + (size_t)(col0 + lrow) * HDIM + lsc * 8;
    char* ldsAw = smem + wave * 1024;                // + slot*16384 (+8192 for j1)
    char* ldsBw = smem + BRING_OFF + wave * 1024;

    auto stageA = [&](int h) {
        const unsigned short* g = gA + (size_t)((h & 1) * 128) * HDIM + (h >> 1) * 64;
        char* l = ldsAw + (h % 5) * ASLOT;
        gload16(g, l);
        gload16(g + 64 * HDIM, l + 8192);
    };
    auto stageB = [&](int h) {
        const unsigned short* g = gB + (size_t)((h & 1) * 128) * HDIM + (h >> 1) * 64;
        char* l = ldsBw + (h % 5) * ASLOT;
        gload16(g, l);
        gload16(g + 64 * HDIM, l + 8192);
    };

    // pnn / epilogue read-side mapping
    const int rrd = q;                    // 0..3
    const int crd = r * 4;                // 0..60
    const f32x4 unv4 = *(const f32x4*)&un[col0 + wn2 * 64 + crd];
    float* pnn_base = pnn + (size_t)(row0 + wm * 128 + rrd) * KNOISE
                          + col0 + wn2 * 64 + crd;

    f32x4 acc[8][4];
    #pragma unroll
    for (int mi = 0; mi < 8; mi++)
        #pragma unroll
        for (int ni = 0; ni < 4; ni++)
            acc[mi][ni] = (f32x4){0.f, 0.f, 0.f, 0.f};

    // prologue: halves 0,1,2 of both matrices; need A0,B0,A1,B1 resident
    stageA(0); stageB(0); stageA(1); stageB(1); stageA(2); stageB(2);
    asm volatile("s_waitcnt vmcnt(4)" ::: "memory");
    __builtin_amdgcn_s_barrier();

    int slotA = wm;              // (2t + wm) % 5
    int slotB = wn2 >> 1;        // (2t + (wn2>>1)) % 5
    const int koff0 = (q * 16) ^ swz;
    const int koff1 = (64 + q * 16) ^ swz;

    for (int t = 0; t < 16; ++t) {
        const char* As = smem + slotA * ASLOT;
        const char* Bs = smem + BRING_OFF + slotB * ASLOT;

        bf16x8 af[4][2], bv[2][2][2];

        // ---- p0 (mih=0, nih=0): read af half 0 (8) + bv[0] (4); stage A(2t+3)
        #pragma unroll
        for (int m4 = 0; m4 < 4; ++m4) {
            const int rb = (m4 * 16 + r) << 7;
            af[m4][0] = *(const bf16x8*)(As + rb + koff0);
            af[m4][1] = *(const bf16x8*)(As + rb + koff1);
        }
        #pragma unroll
        for (int n2 = 0; n2 < 2; ++n2) {
            const int cb = ((wn2 & 1) * 64 + n2 * 16 + r) << 7;
            bv[0][n2][0] = *(const bf16x8*)(Bs + cb + koff0);
            bv[0][n2][1] = *(const bf16x8*)(Bs + cb + koff1);
        }
        if (t <= 14) stageA(2 * t + 3);
        __builtin_amdgcn_s_barrier();
        asm volatile("s_waitcnt lgkmcnt(0)" ::: "memory");
        __builtin_amdgcn_sched_barrier(0);
        __builtin_amdgcn_s_setprio(1);
        #pragma unroll
        for (int m4 = 0; m4 < 4; ++m4)
            #pragma unroll
            for (int n2 = 0; n2 < 2; ++n2) {
                f32x4 c = acc[m4][n2];
                c = __builtin_amdgcn_mfma_f32_16x16x32_bf16(af[m4][0], bv[0][n2][0], c, 0, 0, 0);
                c = __builtin_amdgcn_mfma_f32_16x16x32_bf16(af[m4][1], bv[0][n2][1], c, 0, 0, 0);
                acc[m4][n2] = c;
            }
        __builtin_amdgcn_s_setprio(0);
        __builtin_amdgcn_sched_barrier(0);
        __builtin_amdgcn_s_barrier();

        // ---- p1 (mih=0, nih=1): read bv[1] (4); stage B(2t+3)
        #pragma unroll
        for (int n2 = 0; n2 < 2; ++n2) {
            const int cb = ((wn2 & 1) * 64 + 32 + n2 * 16 + r) << 7;
            bv[1][n2][0] = *(const bf16x8*)(Bs + cb + koff0);
            bv[1][n2][1] = *(const bf16x8*)(Bs + cb + koff1);
        }
        if (t <= 14) stageB(2 * t + 3);
        __builtin_amdgcn_s_barrier();
        asm volatile("s_waitcnt lgkmcnt(0)" ::: "memory");
        __builtin_amdgcn_sched_barrier(0);
        __builtin_amdgcn_s_setprio(1);
        #pragma unroll
        for (int m4 = 0; m4 < 4; ++m4)
            #pragma unroll
            for (int n2 = 0; n2 < 2; ++n2) {
                f32x4 c = acc[m4][2 + n2];
                c = __builtin_amdgcn_mfma_f32_16x16x32_bf16(af[m4][0], bv[1][n2][0], c, 0, 0, 0);
                c = __builtin_amdgcn_mfma_f32_16x16x32_bf16(af[m4][1], bv[1][n2][1], c, 0, 0, 0);
                acc[m4][2 + n2] = c;
            }
        __builtin_amdgcn_s_setprio(0);
        __builtin_amdgcn_sched_barrier(0);
        __builtin_amdgcn_s_barrier();

        // ---- p2 (mih=1, nih=1): read af half 1 (8); pnn store; stage A(2t+4)
        #pragma unroll
        for (int m4 = 0; m4 < 4; ++m4) {
            const int rb = (64 + m4 * 16 + r) << 7;
            af[m4][0] = *(const bf16x8*)(As + rb + koff0);
            af[m4][1] = *(const bf16x8*)(As + rb + koff1);
        }
        {
            float* pb = pnn_base + (size_t)(8 * t) * KNOISE;
            __builtin_nontemporal_store(unv4, (f32x4*)pb);
            __builtin_nontemporal_store(unv4, (f32x4*)(pb + 4 * KNOISE));
        }
        if (t <= 13) stageA(2 * t + 4);
        __builtin_amdgcn_s_barrier();
        asm volatile("s_waitcnt lgkmcnt(0)" ::: "memory");
        __builtin_amdgcn_sched_barrier(0);
        __builtin_amdgcn_s_setprio(1);
        #pragma unroll
        for (int m4 = 0; m4 < 4; ++m4)
            #pragma unroll
            for (int n2 = 0; n2 < 2; ++n2) {
                f32x4 c = acc[4 + m4][2 + n2];
                c = __builtin_amdgcn_mfma_f32_16x16x32_bf16(af[m4][0], bv[1][n2][0], c, 0, 0, 0);
                c = __builtin_amdgcn_mfma_f32_16x16x32_bf16(af[m4][1], bv[1][n2][1], c, 0, 0, 0);
                acc[4 + m4][2 + n2] = c;
            }
        __builtin_amdgcn_s_setprio(0);
        __builtin_amdgcn_sched_barrier(0);
        __builtin_amdgcn_s_barrier();

        // ---- p3 (mih=1, nih=0): no reads; stage B(2t+4); boundary vmcnt
        if (t <= 13) stageB(2 * t + 4);
        __builtin_amdgcn_s_barrier();
        __builtin_amdgcn_s_setprio(1);
        #pragma unroll
        for (int m4 = 0; m4 < 4; ++m4)
            #pragma unroll
            for (int n2 = 0; n2 < 2; ++n2) {
                f32x4 c = acc[4 + m4][n2];
                c = __builtin_amdgcn_mfma_f32_16x16x32_bf16(af[m4][0], bv[0][n2][0], c, 0, 0, 0);
                c = __builtin_amdgcn_mfma_f32_16x16x32_bf16(af[m4][1], bv[0][n2][1], c, 0, 0, 0);
                acc[4 + m4][n2] = c;
            }
        __builtin_amdgcn_s_setprio(0);
        __builtin_amdgcn_sched_barrier(0);
        if (t < 14)       { asm volatile("s_waitcnt vmcnt(6)" ::: "memory"); }
        else if (t == 14) { asm volatile("s_waitcnt vmcnt(2)" ::: "memory"); }
        __builtin_amdgcn_s_barrier();

        slotA += 2; if (slotA >= 5) slotA -= 5;
        slotB += 2; if (slotB >= 5) slotB -= 5;
    }

    // ---- epilogue: exp(acc+bias) -> per-wave LDS transpose -> float4 stores
    float bnv[4];
    #pragma unroll
    for (int ni = 0; ni < 4; ni++)
        bnv[ni] = bn[col0 + wn2 * 64 + ni * 16 + r];

    float* eps = (float*)smem + wave * (16 * EPS_LD);
    #pragma unroll
    for (int mi = 0; mi < 8; ++mi) {
        #pragma unroll
        for (int ni = 0; ni < 4; ++ni)
            #pragma unroll
            for (int j = 0; j < 4; ++j)
                eps[(q * 4 + j) * EPS_LD + ni * 16 + r] = __expf(acc[mi][ni][j] + bnv[ni]);
        __builtin_amdgcn_s_waitcnt(0xc07f);   // lgkmcnt(0) only
        #pragma unroll
        for (int j = 0; j < 4; ++j) {
            f32x4 v = *(f32x4*)&eps[(rrd * 4 + j) * EPS_LD + crd];
            size_t off = (size_t)(row0 + wm * 128 + mi * 16 + rrd * 4 + j) * KNOISE
                       + col0 + wn2 * 64 + crd;
            __builtin_nontemporal_store(v, (f32x4*)&pmn[off]);
        }
        __builtin_amdgcn_s_waitcnt(0xc07f);   // reads done before next mi overwrites
    }
}

// ---------------------------------------------------------------------------
extern "C" void kernel_launch(void* const* d_in, const int* in_sizes, int n_in,
                              void* d_out, int out_size, void* d_ws, size_t ws_size,
                              hipStream_t stream) {
    const float* input   = (const float*)d_in[0];
    const float* weight  = (const float*)d_in[1];
    const float* bias    = (const float*)d_in[2];
    const float* unigram = (const float*)d_in[3];
    const int*   target  = (const int*)d_in[4];
    const int*   noise   = (const int*)d_in[5];

    unsigned short* in_bf = (unsigned short*)d_ws;                    // 16 MB
    unsigned short* wn_bf = in_bf + (size_t)NROWS * HDIM;             // 8 MB
    float* bn = (float*)(wn_bf + (size_t)KNOISE * HDIM);
    float* un = bn + KNOISE;

    float* out = (float*)d_out;
    float* o_pmt = out;
    float* o_pnt = out + NROWS;
    float* o_pmn = out + 2 * NROWS;
    float* o_pnn = o_pmn + (size_t)NROWS * KNOISE;

    static bool attr_done = false;
    if (!attr_done) {
        (void)hipFuncSetAttribute(reinterpret_cast<const void*>(gemm_nce_kernel),
                                  hipFuncAttributeMaxDynamicSharedMemorySize,
                                  SMEM_DYN);
        attr_done = true;
    }

    prep_kernel<<<NROWS + KNOISE, 256, 0, stream>>>(
        input, weight, bias, unigram, target, noise,
        in_bf, wn_bf, bn, un, o_pmt, o_pnt);

    gemm_nce_kernel<<<512, 512, SMEM_DYN, stream>>>(
        in_bf, wn_bf, bn, un, o_pmn, o_pnn);
}

// Round 5
// 439.101 us; speedup vs baseline: 1.0685x; 1.0001x over previous
//
#include <hip/hip_runtime.h>
#include <hip/hip_bf16.h>

// Problem constants (linear_nce): N=8192, H=1024, V=50257, K=4096
#define NROWS 8192
#define HDIM  1024
#define VDIM  50257
#define KNOISE 4096

typedef short  bf16x8 __attribute__((ext_vector_type(8)));
typedef float  f32x4  __attribute__((ext_vector_type(4)));

__device__ __forceinline__ unsigned short f2bf(float x) {
    union { float f; unsigned int u; } v; v.f = x;
    unsigned int r = (v.u + 0x7fffu + ((v.u >> 16) & 1u)) >> 16;
    return (unsigned short)r;
}

// async global->LDS 16B copy: LDS dest is wave-uniform base + lane*16
__device__ __forceinline__ void gload16(const void* g, void* l) {
    __builtin_amdgcn_global_load_lds(
        (const __attribute__((address_space(1))) void*)g,
        (__attribute__((address_space(3))) void*)l, 16, 0, 0);
}

// ---------------------------------------------------------------------------
// Fused prep kernel (UNCHANGED):
//  blocks [0, NROWS):       pmt/pnt fp32 dot for row b; also convert input row
//                           -> bf16 into in_bf.
//  blocks [NROWS, NROWS+K): gather weight[noise] -> bf16 wn_bf, bn, un.
__global__ __launch_bounds__(256) void prep_kernel(
        const float* __restrict__ input,
        const float* __restrict__ weight,
        const float* __restrict__ bias,
        const float* __restrict__ unigram,
        const int* __restrict__ target,
        const int* __restrict__ noise,
        unsigned short* __restrict__ in_bf,
        unsigned short* __restrict__ wn_bf,
        float* __restrict__ bn,
        float* __restrict__ un,
        float* __restrict__ out_pmt,
        float* __restrict__ out_pnt) {
    const int tid = threadIdx.x;
    if (blockIdx.x < NROWS) {
        const int row = blockIdx.x;
        const int t = target[row];
        float4 a = ((const float4*)(input + (size_t)row * HDIM))[tid];
        ushort4 o;
        o.x = f2bf(a.x); o.y = f2bf(a.y); o.z = f2bf(a.z); o.w = f2bf(a.w);
        ((ushort4*)(in_bf + (size_t)row * HDIM))[tid] = o;
        float4 w = ((const float4*)(weight + (size_t)t * HDIM))[tid];
        float s = a.x * w.x + a.y * w.y + a.z * w.z + a.w * w.w;
        #pragma unroll
        for (int off = 32; off > 0; off >>= 1) s += __shfl_down(s, off);
        __shared__ float red[4];
        if ((tid & 63) == 0) red[tid >> 6] = s;
        __syncthreads();
        if (tid == 0) {
            float tot = red[0] + red[1] + red[2] + red[3];
            out_pmt[row] = expf(tot + bias[t]);
            out_pnt[row] = unigram[t];
        }
    } else {
        const int r = blockIdx.x - NROWS;       // 0..K-1
        const int idx = noise[r];
        float4 v = ((const float4*)(weight + (size_t)idx * HDIM))[tid];
        ushort4 o;
        o.x = f2bf(v.x); o.y = f2bf(v.y); o.z = f2bf(v.z); o.w = f2bf(v.w);
        ((ushort4*)(wn_bf + (size_t)r * HDIM))[tid] = o;
        if (tid == 0) { bn[r] = bias[idx]; un[r] = unigram[idx]; }
    }
}

// ---------------------------------------------------------------------------
// GEMM v4: 256x256 tile, BK=64, 512 threads (8 waves, 2Mx4N).
// Changes vs v3c:
//  - bv[1] ds_reads hoisted from p1 into p0 (issued last), with counted
//    lgkmcnt(4) before p0's MFMA cluster: bv1 latency overlaps quad-00 MFMAs;
//    p1 loses its read-wall entirely. Zero VGPR cost (bv1 was whole-tile
//    live anyway). sched_barrier(0) pins the read group in p0.
//  - 8x8-per-XCD block swizzle: each XCD covers an 8 row-strip x 8 col-panel
//    sub-grid (bijective: row=(xcd&3)*8+rloc, col=(xcd>>2)*8+cloc). A+B
//    working set per XCD = 8 MB streams through L2; LLC panel traffic drops
//    ~4x vs the 2-col-panel mapping.
// Tile issue order per tile t (FIFO-critical): A(2t+3) @p0, B(2t+3) @p1,
// {pnn st x2, A(2t+4)} @p2, B(2t+4) @p3; boundary vmcnt(6) leaves
// {st,st,A4,A4,B4,B4} in flight. t==14: vmcnt(2); t==15: none.
// LDS: A-ring 5 x 16 KB half-tiles | B-ring 5 x 16 KB (+81920); half-tile =
// 128 rows x 64 cols bf16, 128 B rows, byte ^= (row&7)<<4 swizzle applied on
// read AND on the pre-swizzled global_load_lds source chunk.
#define BM 256
#define BN 256
#define ASLOT 16384
#define BRING_OFF 81920        // 5 * 16384
#define EPS_LD 68
#define SMEM_DYN 163840        // 160 KiB

__global__ __launch_bounds__(512, 2) void gemm_nce_kernel(
        const unsigned short* __restrict__ A,
        const unsigned short* __restrict__ Bt,
        const float* __restrict__ bn,
        const float* __restrict__ un,
        float* __restrict__ pmn,
        float* __restrict__ pnn) {
    extern __shared__ char smem[];

    const int tid  = threadIdx.x;          // 0..511
    const int wave = tid >> 6;             // 0..7
    const int lane = tid & 63;
    const int wm   = wave >> 2;            // 0..1  (M half)
    const int wn2  = wave & 3;             // 0..3  (N quarter)
    const int r    = lane & 15;
    const int q    = lane >> 4;
    const int swz  = (r & 7) << 4;

    // 8x8-per-XCD swizzle (bijective over 32 row-strips x 16 col-panels)
    const int bid  = blockIdx.x;           // 0..511
    const int xcd  = bid & 7;
    const int jj   = bid >> 3;             // 0..63
    const int rloc = jj & 7;
    const int cloc = jj >> 3;              // 0..7
    const int row0 = (((xcd & 3) << 3) + rloc) * BM;   // 32 strips
    const int col0 = (((xcd >> 2) << 3) + cloc) * BN;  // 16 panels

    // staging per-thread constants (pre-swizzled global source)
    const int lrow   = tid >> 3;                     // 0..63 (row for issue j0)
    const int lchunk = tid & 7;                      // 16B chunk within 128B row
    const int lsc    = lchunk ^ (lrow & 7);          // inverse-swizzled src chunk
    const unsigned short* gA = A  + (size_t)(row0 + lrow) * HDIM + lsc * 8;
    const unsigned short* gB = Bt + (size_t)(col0 + lrow) * HDIM + lsc * 8;
    char* ldsAw = smem + wave * 1024;                // + slot*16384 (+8192 for j1)
    char* ldsBw = smem + BRING_OFF + wave * 1024;

    auto stageA = [&](int h) {
        const unsigned short* g = gA + (size_t)((h & 1) * 128) * HDIM + (h >> 1) * 64;
        char* l = ldsAw + (h % 5) * ASLOT;
        gload16(g, l);
        gload16(g + 64 * HDIM, l + 8192);
    };
    auto stageB = [&](int h) {
        const unsigned short* g = gB + (size_t)((h & 1) * 128) * HDIM + (h >> 1) * 64;
        char* l = ldsBw + (h % 5) * ASLOT;
        gload16(g, l);
        gload16(g + 64 * HDIM, l + 8192);
    };

    // pnn / epilogue read-side mapping
    const int rrd = q;                    // 0..3
    const int crd = r * 4;                // 0..60
    const f32x4 unv4 = *(const f32x4*)&un[col0 + wn2 * 64 + crd];
    float* pnn_base = pnn + (size_t)(row0 + wm * 128 + rrd) * KNOISE
                          + col0 + wn2 * 64 + crd;

    f32x4 acc[8][4];
    #pragma unroll
    for (int mi = 0; mi < 8; mi++)
        #pragma unroll
        for (int ni = 0; ni < 4; ni++)
            acc[mi][ni] = (f32x4){0.f, 0.f, 0.f, 0.f};

    // prologue: halves 0,1,2 of both matrices; need A0,B0,A1,B1 resident
    stageA(0); stageB(0); stageA(1); stageB(1); stageA(2); stageB(2);
    asm volatile("s_waitcnt vmcnt(4)" ::: "memory");
    __builtin_amdgcn_s_barrier();

    int slotA = wm;              // (2t + wm) % 5
    int slotB = wn2 >> 1;        // (2t + (wn2>>1)) % 5
    const int koff0 = (q * 16) ^ swz;
    const int koff1 = (64 + q * 16) ^ swz;

    for (int t = 0; t < 16; ++t) {
        const char* As = smem + slotA * ASLOT;
        const char* Bs = smem + BRING_OFF + slotB * ASLOT;

        bf16x8 af[4][2], bv[2][2][2];

        // ---- p0 (quad 00): read af0 (8) + bv0 (4) + bv1 (4, hoisted, last);
        //      stage A(2t+3); counted lgkmcnt(4) -> bv1 overlaps MFMA.
        #pragma unroll
        for (int m4 = 0; m4 < 4; ++m4) {
            const int rb = (m4 * 16 + r) << 7;
            af[m4][0] = *(const bf16x8*)(As + rb + koff0);
            af[m4][1] = *(const bf16x8*)(As + rb + koff1);
        }
        #pragma unroll
        for (int n2 = 0; n2 < 2; ++n2) {
            const int cb = ((wn2 & 1) * 64 + n2 * 16 + r) << 7;
            bv[0][n2][0] = *(const bf16x8*)(Bs + cb + koff0);
            bv[0][n2][1] = *(const bf16x8*)(Bs + cb + koff1);
        }
        #pragma unroll
        for (int n2 = 0; n2 < 2; ++n2) {
            const int cb = ((wn2 & 1) * 64 + 32 + n2 * 16 + r) << 7;
            bv[1][n2][0] = *(const bf16x8*)(Bs + cb + koff0);
            bv[1][n2][1] = *(const bf16x8*)(Bs + cb + koff1);
        }
        __builtin_amdgcn_sched_barrier(0);   // pin the read group in p0
        if (t <= 14) stageA(2 * t + 3);
        __builtin_amdgcn_s_barrier();
        asm volatile("s_waitcnt lgkmcnt(4)" ::: "memory");  // af0+bv0 done
        __builtin_amdgcn_sched_barrier(0);
        __builtin_amdgcn_s_setprio(1);
        #pragma unroll
        for (int m4 = 0; m4 < 4; ++m4)
            #pragma unroll
            for (int n2 = 0; n2 < 2; ++n2) {
                f32x4 c = acc[m4][n2];
                c = __builtin_amdgcn_mfma_f32_16x16x32_bf16(af[m4][0], bv[0][n2][0], c, 0, 0, 0);
                c = __builtin_amdgcn_mfma_f32_16x16x32_bf16(af[m4][1], bv[0][n2][1], c, 0, 0, 0);
                acc[m4][n2] = c;
            }
        __builtin_amdgcn_s_setprio(0);
        __builtin_amdgcn_sched_barrier(0);
        __builtin_amdgcn_s_barrier();

        // ---- p1 (quad 01): no reads; stage B(2t+3)
        if (t <= 14) stageB(2 * t + 3);
        __builtin_amdgcn_s_barrier();
        asm volatile("s_waitcnt lgkmcnt(0)" ::: "memory");  // bv1 done
        __builtin_amdgcn_sched_barrier(0);
        __builtin_amdgcn_s_setprio(1);
        #pragma unroll
        for (int m4 = 0; m4 < 4; ++m4)
            #pragma unroll
            for (int n2 = 0; n2 < 2; ++n2) {
                f32x4 c = acc[m4][2 + n2];
                c = __builtin_amdgcn_mfma_f32_16x16x32_bf16(af[m4][0], bv[1][n2][0], c, 0, 0, 0);
                c = __builtin_amdgcn_mfma_f32_16x16x32_bf16(af[m4][1], bv[1][n2][1], c, 0, 0, 0);
                acc[m4][2 + n2] = c;
            }
        __builtin_amdgcn_s_setprio(0);
        __builtin_amdgcn_sched_barrier(0);
        __builtin_amdgcn_s_barrier();

        // ---- p2 (quad 11): read af1 (8); pnn store; stage A(2t+4)
        #pragma unroll
        for (int m4 = 0; m4 < 4; ++m4) {
            const int rb = (64 + m4 * 16 + r) << 7;
            af[m4][0] = *(const bf16x8*)(As + rb + koff0);
            af[m4][1] = *(const bf16x8*)(As + rb + koff1);
        }
        __builtin_amdgcn_sched_barrier(0);
        {
            float* pb = pnn_base + (size_t)(8 * t) * KNOISE;
            __builtin_nontemporal_store(unv4, (f32x4*)pb);
            __builtin_nontemporal_store(unv4, (f32x4*)(pb + 4 * KNOISE));
        }
        if (t <= 13) stageA(2 * t + 4);
        __builtin_amdgcn_s_barrier();
        asm volatile("s_waitcnt lgkmcnt(0)" ::: "memory");
        __builtin_amdgcn_sched_barrier(0);
        __builtin_amdgcn_s_setprio(1);
        #pragma unroll
        for (int m4 = 0; m4 < 4; ++m4)
            #pragma unroll
            for (int n2 = 0; n2 < 2; ++n2) {
                f32x4 c = acc[4 + m4][2 + n2];
                c = __builtin_amdgcn_mfma_f32_16x16x32_bf16(af[m4][0], bv[1][n2][0], c, 0, 0, 0);
                c = __builtin_amdgcn_mfma_f32_16x16x32_bf16(af[m4][1], bv[1][n2][1], c, 0, 0, 0);
                acc[4 + m4][2 + n2] = c;
            }
        __builtin_amdgcn_s_setprio(0);
        __builtin_amdgcn_sched_barrier(0);
        __builtin_amdgcn_s_barrier();

        // ---- p3 (quad 10): no reads; stage B(2t+4); boundary vmcnt
        if (t <= 13) stageB(2 * t + 4);
        __builtin_amdgcn_s_barrier();
        __builtin_amdgcn_s_setprio(1);
        #pragma unroll
        for (int m4 = 0; m4 < 4; ++m4)
            #pragma unroll
            for (int n2 = 0; n2 < 2; ++n2) {
                f32x4 c = acc[4 + m4][n2];
                c = __builtin_amdgcn_mfma_f32_16x16x32_bf16(af[m4][0], bv[0][n2][0], c, 0, 0, 0);
                c = __builtin_amdgcn_mfma_f32_16x16x32_bf16(af[m4][1], bv[0][n2][1], c, 0, 0, 0);
                acc[4 + m4][n2] = c;
            }
        __builtin_amdgcn_s_setprio(0);
        __builtin_amdgcn_sched_barrier(0);
        if (t < 14)       { asm volatile("s_waitcnt vmcnt(6)" ::: "memory"); }
        else if (t == 14) { asm volatile("s_waitcnt vmcnt(2)" ::: "memory"); }
        __builtin_amdgcn_s_barrier();

        slotA += 2; if (slotA >= 5) slotA -= 5;
        slotB += 2; if (slotB >= 5) slotB -= 5;
    }

    // ---- epilogue: exp(acc+bias) -> per-wave LDS transpose -> float4 stores
    float bnv[4];
    #pragma unroll
    for (int ni = 0; ni < 4; ni++)
        bnv[ni] = bn[col0 + wn2 * 64 + ni * 16 + r];

    float* eps = (float*)smem + wave * (16 * EPS_LD);
    #pragma unroll
    for (int mi = 0; mi < 8; ++mi) {
        #pragma unroll
        for (int ni = 0; ni < 4; ++ni)
            #pragma unroll
            for (int j = 0; j < 4; ++j)
                eps[(q * 4 + j) * EPS_LD + ni * 16 + r] = __expf(acc[mi][ni][j] + bnv[ni]);
        __builtin_amdgcn_s_waitcnt(0xc07f);   // lgkmcnt(0) only
        #pragma unroll
        for (int j = 0; j < 4; ++j) {
            f32x4 v = *(f32x4*)&eps[(rrd * 4 + j) * EPS_LD + crd];
            size_t off = (size_t)(row0 + wm * 128 + mi * 16 + rrd * 4 + j) * KNOISE
                       + col0 + wn2 * 64 + crd;
            __builtin_nontemporal_store(v, (f32x4*)&pmn[off]);
        }
        __builtin_amdgcn_s_waitcnt(0xc07f);   // reads done before next mi overwrites
    }
}

// ---------------------------------------------------------------------------
extern "C" void kernel_launch(void* const* d_in, const int* in_sizes, int n_in,
                              void* d_out, int out_size, void* d_ws, size_t ws_size,
                              hipStream_t stream) {
    const float* input   = (const float*)d_in[0];
    const float* weight  = (const float*)d_in[1];
    const float* bias    = (const float*)d_in[2];
    const float* unigram = (const float*)d_in[3];
    const int*   target  = (const int*)d_in[4];
    const int*   noise   = (const int*)d_in[5];

    unsigned short* in_bf = (unsigned short*)d_ws;                    // 16 MB
    unsigned short* wn_bf = in_bf + (size_t)NROWS * HDIM;             // 8 MB
    float* bn = (float*)(wn_bf + (size_t)KNOISE * HDIM);
    float* un = bn + KNOISE;

    float* out = (float*)d_out;
    float* o_pmt = out;
    float* o_pnt = out + NROWS;
    float* o_pmn = out + 2 * NROWS;
    float* o_pnn = o_pmn + (size_t)NROWS * KNOISE;

    static bool attr_done = false;
    if (!attr_done) {
        (void)hipFuncSetAttribute(reinterpret_cast<const void*>(gemm_nce_kernel),
                                  hipFuncAttributeMaxDynamicSharedMemorySize,
                                  SMEM_DYN);
        attr_done = true;
    }

    prep_kernel<<<NROWS + KNOISE, 256, 0, stream>>>(
        input, weight, bias, unigram, target, noise,
        in_bf, wn_bf, bn, un, o_pmt, o_pnt);

    gemm_nce_kernel<<<512, 512, SMEM_DYN, stream>>>(
        in_bf, wn_bf, bn, un, o_pmn, o_pnn);
}